// Round 10
// baseline (383.039 us; speedup 1.0000x reference)
//
#include <hip/hip_runtime.h>
#include <math.h>

#define BATCH 2
#define SEQ   2048
#define EMB   1024
#define NHEAD 16
#define DHEAD 64
#define MROWS (BATCH*SEQ)
#define QKS   2048          // Q|K packed row stride (Q cols 0..1023, K 1024..2047)

typedef unsigned int  uint;
typedef unsigned short ushort;
typedef __attribute__((ext_vector_type(8))) short short8;
typedef __attribute__((ext_vector_type(4))) float f32x4;

__device__ __forceinline__ float exp2_fast(float x) {
    return __builtin_amdgcn_exp2f(x);
}

// ---------------- positional encoding table ----------------
__global__ void pos_init(float* __restrict__ pos) {
    int s = blockIdx.x;
    int d = threadIdx.x;              // 0..63
    int i = d >> 1;
    float expo  = (float)(2 * i) / (float)DHEAD;
    float scale = 1.0f / (powf(10000.0f, expo) + 1.1920928955078125e-07f);
    float ang   = (float)s * scale;
    pos[s * DHEAD + d] = (d & 1) ? cosf(ang) : sinf(ang);
}

// ---------------- bf16 helpers ----------------
__device__ __forceinline__ uint pack_bf16x2(float a, float b) {
    union { float f; uint u; } x, y;
    x.f = a; y.f = b;
    uint ua = x.u + 0x7fffu + ((x.u >> 16) & 1u);   // RNE
    uint ub = y.u + 0x7fffu + ((y.u >> 16) & 1u);
    return (ua >> 16) | (ub & 0xffff0000u);
}
__device__ __forceinline__ ushort bf16_1(float a) {
    union { float f; uint u; } x; x.f = a;
    return (ushort)((x.u + 0x7fffu + ((x.u >> 16) & 1u)) >> 16);
}

// async global->LDS, 16B per lane
__device__ __forceinline__ void gll16(const ushort* g, ushort* l) {
    __builtin_amdgcn_global_load_lds(
        (const __attribute__((address_space(1))) uint*)g,
        (__attribute__((address_space(3))) uint*)l, 16, 0, 0);
}

// ---------------- fp32 -> bf16 (rowmajor) ----------------
__global__ __launch_bounds__(256) void cvt_bf16(
    const float* __restrict__ in, ushort* __restrict__ out, int n2) {
    int gid = blockIdx.x * 256 + threadIdx.x;
    if (gid < n2) {
        float2 v = ((const float2*)in)[gid];
        ((uint*)out)[gid] = pack_bf16x2(v.x, v.y);
    }
}

// ------- all 4 weights: W[K][N] fp32 -> Wt[N][K] bf16 (transpose) ----------
__global__ __launch_bounds__(256) void wt_bf16_all(
    const float* __restrict__ Wq, const float* __restrict__ Wk,
    const float* __restrict__ Wv, const float* __restrict__ Wo,
    ushort* __restrict__ Wqkvt, ushort* __restrict__ Wot) {
    __shared__ float tile[32][33];
    const int which = blockIdx.z;
    const float* W = (which == 0) ? Wq : (which == 1) ? Wk : (which == 2) ? Wv : Wo;
    ushort* Wt = (which < 3) ? (Wqkvt + (size_t)which * 1024 * EMB) : Wot;
    const int c0 = blockIdx.x * 32;
    const int r0 = blockIdx.y * 32;
    const int tx = threadIdx.x & 31;
    const int ty = threadIdx.x >> 5;
#pragma unroll
    for (int i = 0; i < 4; ++i)
        tile[ty + i * 8][tx] = W[(size_t)(r0 + ty + i * 8) * EMB + c0 + tx];
    __syncthreads();
#pragma unroll
    for (int i = 0; i < 4; ++i)
        Wt[(size_t)(c0 + ty + i * 8) * EMB + r0 + tx] = bf16_1(tile[tx][ty + i * 8]);
}

// ------- templated bf16 MFMA GEMM: C = A @ Bt^T, TN=128, TM = TMT ----------
// posmode=1 (QKV): col<1024 -> Q=(v+pos)*SCLQ bf16 to QK; col<2048 -> K=v+pos
// bf16 to QK; col>=2048 -> V transposed to Vt[bh][d][s] (packed uint2 in s).
// posmode=0: plain fp32 C[row*N+col].
#define TK 32
#define SCLQ (0.03125f * 1.44269504088896f)

template<int TMT>
__global__ __launch_bounds__(256) void gemm_mfma_t(
    const ushort* __restrict__ A, const ushort* __restrict__ Bt,
    void* __restrict__ Cv, ushort* __restrict__ VtOut,
    const float* __restrict__ pos, int posmode, int N, int K) {
    constexpr int MI = TMT / 32;
    __shared__ ushort As[TMT * TK];
    __shared__ ushort Bs[128 * TK];

    const int t    = threadIdx.x;
    const int lane = t & 63, w = t >> 6;
    const int quad = lane >> 4, l15 = lane & 15;
    const int bm = blockIdx.x * TMT, bn = blockIdx.y * 128;
    const int wm = (w & 1) * (TMT / 2), wn = (w >> 1) * 64;
    const int r0 = t >> 2, kp = (t & 3) * 8;

    f32x4 acc[MI][4];
#pragma unroll
    for (int mi = 0; mi < MI; ++mi)
#pragma unroll
        for (int ni = 0; ni < 4; ++ni)
            acc[mi][ni] = (f32x4){0.f, 0.f, 0.f, 0.f};

    for (int k0 = 0; k0 < K; k0 += TK) {
        __syncthreads();
#pragma unroll
        for (int i = 0; i < TMT / 64; ++i)
            gll16(A + (size_t)(bm + i * 64 + r0) * K + k0 + kp, &As[i * 2048 + t * 8]);
#pragma unroll
        for (int i = 0; i < 2; ++i)
            gll16(Bt + (size_t)(bn + i * 64 + r0) * K + k0 + kp, &Bs[i * 2048 + t * 8]);
        __syncthreads();

        short8 af[MI], bfv[4];
#pragma unroll
        for (int mi = 0; mi < MI; ++mi)
            af[mi] = *(const short8*)&As[(wm + mi * 16 + l15) * TK + quad * 8];
#pragma unroll
        for (int ni = 0; ni < 4; ++ni)
            bfv[ni] = *(const short8*)&Bs[(wn + ni * 16 + l15) * TK + quad * 8];
#pragma unroll
        for (int mi = 0; mi < MI; ++mi)
#pragma unroll
            for (int ni = 0; ni < 4; ++ni)
                acc[mi][ni] = __builtin_amdgcn_mfma_f32_16x16x32_bf16(
                    af[mi], bfv[ni], acc[mi][ni], 0, 0, 0);
    }

#pragma unroll
    for (int mi = 0; mi < MI; ++mi) {
        const int row0 = bm + wm + mi * 16 + quad * 4;
#pragma unroll
        for (int ni = 0; ni < 4; ++ni) {
            const int col = bn + wn + ni * 16 + l15;
            if (!posmode) {
#pragma unroll
                for (int r = 0; r < 4; ++r)
                    ((float*)Cv)[(size_t)(row0 + r) * N + col] = acc[mi][ni][r];
            } else if (col < 2048) {
#pragma unroll
                for (int r = 0; r < 4; ++r) {
                    const int row = row0 + r;
                    const int s   = row & (SEQ - 1);
                    float v = acc[mi][ni][r] + pos[s * DHEAD + (col & 63)];
                    if (col < 1024) v *= SCLQ;
                    ((ushort*)Cv)[(size_t)row * QKS + col] = bf16_1(v);
                }
            } else {
                // V -> Vt[bh][d][s], 4 consecutive s packed
                const int hh = (col >> 6) & 15;
                const int d  = col & 63;
                const int bb = row0 >> 11;
                const int s0 = row0 & (SEQ - 1);
                uint2 u;
                u.x = pack_bf16x2(acc[mi][ni][0], acc[mi][ni][1]);
                u.y = pack_bf16x2(acc[mi][ni][2], acc[mi][ni][3]);
                *(uint2*)&VtOut[((size_t)(bb * 16 + hh) * 64 + d) * SEQ + s0] = u;
            }
        }
    }
}

// ---- MFMA flash attention v6: paired 32-row q-tiles, 2 waves, LDS K+V -----
// block: q-tiles (p, 63-p) -> uniform 33 K-tile iters; 1024 blocks (4/CU).
// wave owns 16 q-rows (R7-proven inner loop); K/V staged to LDS w/ reg
// prefetch, shared by both waves; P per-wave private region.
#define APAD 72

__global__ __launch_bounds__(128) void attn_mfma6(
    const ushort* __restrict__ QK, const ushort* __restrict__ Vt,
    ushort* __restrict__ AOb) {
    __shared__ ushort Ks[64 * APAD];
    __shared__ ushort Vs[64 * APAD];
    __shared__ ushort Ps[2 * 16 * APAD];

    const int p  = blockIdx.x;            // pair 0..31
    const int bh = blockIdx.y;
    const int b  = bh >> 4, hd = bh & 15;
    const int t  = threadIdx.x;
    const int lane = t & 63, w = t >> 6;  // w = 0,1
    const int quad = lane >> 4, l15 = lane & 15;
    ushort* Pw = &Ps[w * 16 * APAD];

    const size_t qkbase = (size_t)b * SEQ * QKS + hd * 64;
    const ushort* Qp  = QK + qkbase;
    const ushort* Kp  = QK + qkbase + 1024;
    const ushort* Vbp = Vt + (size_t)bh * 64 * SEQ;

    const int sr = t >> 1;                // staging row 0..63
    const int sc = (t & 1) * 32;          // 0 or 32 (ushorts)

#pragma unroll
    for (int ph = 0; ph < 2; ++ph) {
        const int qt = ph ? (63 - p) : p; // 32-row q-tile

        // Q fragments direct from global (pre-scaled by SCLQ in GEMM)
        const ushort* qp = Qp + (size_t)(qt * 32 + w * 16 + l15) * QKS + quad * 8;
        const short8 bq0 = *(const short8*)qp;
        const short8 bq1 = *(const short8*)(qp + 32);

        f32x4 acc_o[4];
#pragma unroll
        for (int nd = 0; nd < 4; ++nd) acc_o[nd] = (f32x4){0.f, 0.f, 0.f, 0.f};
        float m_l = -3.0e38f, l_l = 0.f;  // state for q = qt*32 + w*16 + l15
        const int qrow = qt * 32 + w * 16 + l15;
        const int ktl  = qt >> 1;         // last (diagonal) 64-key tile

        // prefetch kt=0
        uint4 ka[4], va[4];
#pragma unroll
        for (int j = 0; j < 4; ++j) {
            ka[j] = *(const uint4*)(Kp + (size_t)sr * QKS + sc + j * 8);
            va[j] = *(const uint4*)(Vbp + (size_t)sr * SEQ + sc + j * 8);
        }

        for (int kt = 0; kt <= ktl; ++kt) {
            __syncthreads();
#pragma unroll
            for (int j = 0; j < 4; ++j) {
                *(uint4*)&Ks[sr * APAD + sc + j * 8] = ka[j];
                *(uint4*)&Vs[sr * APAD + sc + j * 8] = va[j];
            }
            const int ktn = (kt < ktl) ? kt + 1 : ktl;
#pragma unroll
            for (int j = 0; j < 4; ++j) {
                ka[j] = *(const uint4*)(Kp + (size_t)(ktn * 64 + sr) * QKS + sc + j * 8);
                va[j] = *(const uint4*)(Vbp + (size_t)sr * SEQ + ktn * 64 + sc + j * 8);
            }
            __syncthreads();

            // ---- S^T = K Q^T : lane holds (key=kg*16+quad*4+r, q=l15) ----
            float sv[4][4];
            float mloc = m_l;
            const bool diag = (kt == ktl);
#pragma unroll
            for (int kg = 0; kg < 4; ++kg) {
                const short8 ak0 = *(const short8*)&Ks[(kg * 16 + l15) * APAD + quad * 8];
                const short8 ak1 = *(const short8*)&Ks[(kg * 16 + l15) * APAD + 32 + quad * 8];
                f32x4 a = (f32x4){0.f, 0.f, 0.f, 0.f};
                a = __builtin_amdgcn_mfma_f32_16x16x32_bf16(ak0, bq0, a, 0, 0, 0);
                a = __builtin_amdgcn_mfma_f32_16x16x32_bf16(ak1, bq1, a, 0, 0, 0);
                if (diag) {
                    const int keyb = kt * 64 + kg * 16 + quad * 4;
#pragma unroll
                    for (int r = 0; r < 4; ++r) {
                        float v = (keyb + r > qrow) ? -3.0e38f : a[r];
                        sv[kg][r] = v;
                        mloc = fmaxf(mloc, v);
                    }
                } else {
#pragma unroll
                    for (int r = 0; r < 4; ++r) {
                        sv[kg][r] = a[r];
                        mloc = fmaxf(mloc, a[r]);
                    }
                }
            }
            mloc = fmaxf(mloc, __shfl_xor(mloc, 16, 64));
            mloc = fmaxf(mloc, __shfl_xor(mloc, 32, 64));
            const float alpha = exp2_fast(m_l - mloc);
            m_l = mloc;
            float rs = 0.f;
#pragma unroll
            for (int kg = 0; kg < 4; ++kg)
#pragma unroll
                for (int r = 0; r < 4; ++r) {
                    float pv = exp2_fast(sv[kg][r] - mloc);
                    sv[kg][r] = pv;
                    rs += pv;
                }
            rs += __shfl_xor(rs, 16, 64);
            rs += __shfl_xor(rs, 32, 64);
            l_l = l_l * alpha + rs;

            float av[4];
#pragma unroll
            for (int r = 0; r < 4; ++r) av[r] = __shfl(alpha, quad * 4 + r, 64);
#pragma unroll
            for (int nd = 0; nd < 4; ++nd)
#pragma unroll
                for (int r = 0; r < 4; ++r) acc_o[nd][r] *= av[r];

            // ---- P: C-layout -> A-layout via private per-wave LDS ----
#pragma unroll
            for (int kg = 0; kg < 4; ++kg) {
                uint2 u;
                u.x = pack_bf16x2(sv[kg][0], sv[kg][1]);
                u.y = pack_bf16x2(sv[kg][2], sv[kg][3]);
                *(uint2*)&Pw[l15 * APAD + kg * 16 + quad * 4] = u;
            }
            const short8 pa0 = *(const short8*)&Pw[l15 * APAD + quad * 8];
            const short8 pa1 = *(const short8*)&Pw[l15 * APAD + 32 + quad * 8];
#pragma unroll
            for (int nd = 0; nd < 4; ++nd) {
                const short8 bv0 = *(const short8*)&Vs[(nd * 16 + l15) * APAD + quad * 8];
                const short8 bv1 = *(const short8*)&Vs[(nd * 16 + l15) * APAD + 32 + quad * 8];
                acc_o[nd] = __builtin_amdgcn_mfma_f32_16x16x32_bf16(pa0, bv0, acc_o[nd], 0, 0, 0);
                acc_o[nd] = __builtin_amdgcn_mfma_f32_16x16x32_bf16(pa1, bv1, acc_o[nd], 0, 0, 0);
            }
        }

        // ---- epilogue ----
        float linv[4];
#pragma unroll
        for (int r = 0; r < 4; ++r) linv[r] = 1.0f / __shfl(l_l, quad * 4 + r, 64);
#pragma unroll
        for (int nd = 0; nd < 4; ++nd)
#pragma unroll
            for (int r = 0; r < 4; ++r) {
                const int row = qt * 32 + w * 16 + quad * 4 + r;
                AOb[(size_t)(b * SEQ + row) * EMB + hd * 64 + nd * 16 + l15] =
                    bf16_1(acc_o[nd][r] * linv[r]);
            }
    }
}

// ---------------- fp32 fallback GEMM ----------------
#define BM 64
#define BN 64
#define BK 16

__global__ __launch_bounds__(256) void gemm_f32(
    const float* __restrict__ A, const float* __restrict__ B,
    float* __restrict__ C, const float* __restrict__ pos, int addpos,
    int M, int N, int K) {
    __shared__ float As[BK][BM];
    __shared__ float Bs[BK][BN];
    const int tid = threadIdx.x;
    const int bm  = blockIdx.x * BM;
    const int bn  = blockIdx.y * BN;
    const int tx  = tid & 15;
    const int ty  = tid >> 4;
    const int arow = tid >> 2;
    const int acol = (tid & 3) << 2;
    const int brow = tid >> 4;
    const int bcol = (tid & 15) << 2;
    float acc[4][4] = {{0.f}};
    const float* Aptr = A + (size_t)(bm + arow) * K + acol;
    const float* Bptr = B + (size_t)brow * N + bn + bcol;
    for (int k0 = 0; k0 < K; k0 += BK) {
        float4 av = *(const float4*)(Aptr + k0);
        float4 bv = *(const float4*)(Bptr + (size_t)k0 * N);
        __syncthreads();
        As[acol + 0][arow] = av.x;
        As[acol + 1][arow] = av.y;
        As[acol + 2][arow] = av.z;
        As[acol + 3][arow] = av.w;
        *(float4*)&Bs[brow][bcol] = bv;
        __syncthreads();
#pragma unroll
        for (int kk = 0; kk < BK; ++kk) {
            float4 a = *(const float4*)&As[kk][ty << 2];
            float4 b = *(const float4*)&Bs[kk][tx << 2];
            float aa[4] = {a.x, a.y, a.z, a.w};
            float bb[4] = {b.x, b.y, b.z, b.w};
#pragma unroll
            for (int i = 0; i < 4; ++i)
#pragma unroll
                for (int j = 0; j < 4; ++j)
                    acc[i][j] += aa[i] * bb[j];
        }
    }
#pragma unroll
    for (int i = 0; i < 4; ++i) {
        int m = bm + (ty << 2) + i;
        int n = bn + (tx << 2);
        float4 v = make_float4(acc[i][0], acc[i][1], acc[i][2], acc[i][3]);
        if (addpos) {
            int s = m & (SEQ - 1);
            int d = n & (DHEAD - 1);
            float4 p = *(const float4*)&pos[s * DHEAD + d];
            v.x += p.x; v.y += p.y; v.z += p.z; v.w += p.w;
        }
        *(float4*)&C[(size_t)m * N + n] = v;
    }
}

// ---------------- fp32 fallback attention ----------------
#define QT 128
#define KT 32
__global__ __launch_bounds__(QT) void attn_fwd(
    const float* __restrict__ Q, const float* __restrict__ Kg,
    const float* __restrict__ V, float* __restrict__ O) {
    __shared__ float Ks[KT][DHEAD];
    __shared__ float Vs[KT][DHEAD];
    const int t    = threadIdx.x;
    const int q0   = blockIdx.x * QT;
    const int bh   = blockIdx.y;
    const int b    = bh >> 4;
    const int h    = bh & 15;
    const int qrow = q0 + t;
    const size_t base = (size_t)b * SEQ * EMB + (size_t)h * DHEAD;
    float4 q4[16], o4[16];
#pragma unroll
    for (int i = 0; i < 16; ++i) {
        q4[i] = *(const float4*)&Q[base + (size_t)qrow * EMB + i * 4];
        o4[i] = make_float4(0.f, 0.f, 0.f, 0.f);
    }
    float m_i = -3.0e38f, l_i = 0.0f;
    const float scale = 0.03125f;
    const int kend = q0 + QT;
    for (int k0 = 0; k0 < kend; k0 += KT) {
        __syncthreads();
#pragma unroll
        for (int i = 0; i < 4; ++i) {
            int idx = t + i * QT;
            int r = idx >> 4;
            int c = (idx & 15) << 2;
            *(float4*)&Ks[r][c] = *(const float4*)&Kg[base + (size_t)(k0 + r) * EMB + c];
            *(float4*)&Vs[r][c] = *(const float4*)&V [base + (size_t)(k0 + r) * EMB + c];
        }
        __syncthreads();
        float sv[KT];
        float mt = m_i;
#pragma unroll
        for (int j = 0; j < KT; ++j) {
            const float4* kr = (const float4*)Ks[j];
            float dot = 0.f;
#pragma unroll
            for (int dd = 0; dd < 16; ++dd) {
                float4 kv = kr[dd];
                dot += q4[dd].x * kv.x + q4[dd].y * kv.y +
                       q4[dd].z * kv.z + q4[dd].w * kv.w;
            }
            sv[j] = (k0 + j <= qrow) ? dot * scale : -3.0e38f;
            mt = fmaxf(mt, sv[j]);
        }
        float corr = __expf(m_i - mt);
        l_i *= corr;
#pragma unroll
        for (int i = 0; i < 16; ++i) {
            o4[i].x *= corr; o4[i].y *= corr; o4[i].z *= corr; o4[i].w *= corr;
        }
#pragma unroll
        for (int j = 0; j < KT; ++j) {
            float pp = __expf(sv[j] - mt);
            l_i += pp;
            const float4* vr = (const float4*)Vs[j];
#pragma unroll
            for (int dd = 0; dd < 16; ++dd) {
                float4 vv = vr[dd];
                o4[dd].x += pp * vv.x; o4[dd].y += pp * vv.y;
                o4[dd].z += pp * vv.z; o4[dd].w += pp * vv.w;
            }
        }
        m_i = mt;
    }
    float inv = 1.0f / l_i;
#pragma unroll
    for (int i = 0; i < 16; ++i) {
        float4 v = o4[i];
        v.x *= inv; v.y *= inv; v.z *= inv; v.w *= inv;
        *(float4*)&O[base + (size_t)qrow * EMB + i * 4] = v;
    }
}

// ---------------- launch ----------------
extern "C" void kernel_launch(void* const* d_in, const int* in_sizes, int n_in,
                              void* d_out, int out_size, void* d_ws, size_t ws_size,
                              hipStream_t stream) {
    const float* x  = (const float*)d_in[0];
    const float* Wq = (const float*)d_in[1];
    const float* Wk = (const float*)d_in[2];
    const float* Wv = (const float*)d_in[3];
    const float* Wo = (const float*)d_in[4];
    float* out = (float*)d_out;

    char* ws = (char*)d_ws;
    size_t off = 0;
    float*  pos   = (float*)(ws + off);  off += (size_t)SEQ * DHEAD * 4;
    ushort* xb    = (ushort*)(ws + off); off += (size_t)MROWS * EMB * 2;
    ushort* Wqkvt = (ushort*)(ws + off); off += (size_t)3072 * EMB * 2;
    ushort* Wot   = (ushort*)(ws + off); off += (size_t)EMB * EMB * 2;
    ushort* QKb   = (ushort*)(ws + off); off += (size_t)MROWS * QKS * 2;
    ushort* Vtp   = (ushort*)(ws + off); off += (size_t)MROWS * EMB * 2;
    ushort* AOb   = (ushort*)(ws + off); off += (size_t)MROWS * EMB * 2;
    const bool use_bf16 = off <= ws_size;

    const int M = MROWS, K = EMB;

    pos_init<<<SEQ, DHEAD, 0, stream>>>(pos);

    if (use_bf16) {
        const int n2 = MROWS * EMB / 2;
        cvt_bf16<<<n2 / 256, 256, 0, stream>>>(x, xb, n2);
        wt_bf16_all<<<dim3(EMB / 32, EMB / 32, 4), 256, 0, stream>>>(
            Wq, Wk, Wv, Wo, Wqkvt, Wot);

        // fused QKV projection: Q/K -> QKb (stride 2048, +pos, Q*scl),
        // V -> Vtp transposed [bh][d][s]
        gemm_mfma_t<128><<<dim3(M / 128, 3072 / 128), 256, 0, stream>>>(
            xb, Wqkvt, QKb, Vtp, pos, 1, 3072, K);

        attn_mfma6<<<dim3(32, BATCH * NHEAD), 128, 0, stream>>>(QKb, Vtp, AOb);

        // Wo GEMM: TM=64 -> 512 blocks (2/CU)
        gemm_mfma_t<64><<<dim3(M / 64, EMB / 128), 256, 0, stream>>>(
            AOb, Wot, out, nullptr, pos, 0, EMB, K);
    } else {
        // fp32 fallback
        size_t f = 0;
        float* posf = (float*)(ws + f); f += (size_t)SEQ * DHEAD * 4;
        float* Qb = (float*)(ws + f); f += (size_t)MROWS * EMB * 4;
        float* Kb = (float*)(ws + f); f += (size_t)MROWS * EMB * 4;
        float* Vb = (float*)(ws + f); f += (size_t)MROWS * EMB * 4;
        float* AO = (float*)(ws + f);
        dim3 g(M / BM, EMB / BN);
        gemm_f32<<<g, 256, 0, stream>>>(x, Wq, Qb, posf, 1, M, EMB, K);
        gemm_f32<<<g, 256, 0, stream>>>(x, Wk, Kb, posf, 1, M, EMB, K);
        gemm_f32<<<g, 256, 0, stream>>>(x, Wv, Vb, posf, 0, M, EMB, K);
        attn_fwd<<<dim3(SEQ / QT, BATCH * NHEAD), QT, 0, stream>>>(Qb, Kb, Vb, AO);
        gemm_f32<<<g, 256, 0, stream>>>(AO, Wo, out, posf, 0, M, EMB, K);
    }
}

// Round 11
// 378.000 us; speedup vs baseline: 1.0133x; 1.0133x over previous
//
#include <hip/hip_runtime.h>
#include <math.h>

#define BATCH 2
#define SEQ   2048
#define EMB   1024
#define NHEAD 16
#define DHEAD 64
#define MROWS (BATCH*SEQ)
#define QKS   2048          // Q|K packed row stride (Q cols 0..1023, K 1024..2047)

typedef unsigned int  uint;
typedef unsigned short ushort;
typedef __attribute__((ext_vector_type(8))) short short8;
typedef __attribute__((ext_vector_type(4))) float f32x4;

__device__ __forceinline__ float exp2_fast(float x) {
    return __builtin_amdgcn_exp2f(x);
}

// ---------------- positional encoding table ----------------
__global__ void pos_init(float* __restrict__ pos) {
    int s = blockIdx.x;
    int d = threadIdx.x;              // 0..63
    int i = d >> 1;
    float expo  = (float)(2 * i) / (float)DHEAD;
    float scale = 1.0f / (powf(10000.0f, expo) + 1.1920928955078125e-07f);
    float ang   = (float)s * scale;
    pos[s * DHEAD + d] = (d & 1) ? cosf(ang) : sinf(ang);
}

// ---------------- bf16 helpers ----------------
__device__ __forceinline__ uint pack_bf16x2(float a, float b) {
    union { float f; uint u; } x, y;
    x.f = a; y.f = b;
    uint ua = x.u + 0x7fffu + ((x.u >> 16) & 1u);   // RNE
    uint ub = y.u + 0x7fffu + ((y.u >> 16) & 1u);
    return (ua >> 16) | (ub & 0xffff0000u);
}
__device__ __forceinline__ ushort bf16_1(float a) {
    union { float f; uint u; } x; x.f = a;
    return (ushort)((x.u + 0x7fffu + ((x.u >> 16) & 1u)) >> 16);
}

// async global->LDS, 16B per lane
__device__ __forceinline__ void gll16(const ushort* g, ushort* l) {
    __builtin_amdgcn_global_load_lds(
        (const __attribute__((address_space(1))) uint*)g,
        (__attribute__((address_space(3))) uint*)l, 16, 0, 0);
}

// ---------------- fp32 -> bf16 (rowmajor) ----------------
__global__ __launch_bounds__(256) void cvt_bf16(
    const float* __restrict__ in, ushort* __restrict__ out, int n2) {
    int gid = blockIdx.x * 256 + threadIdx.x;
    if (gid < n2) {
        float2 v = ((const float2*)in)[gid];
        ((uint*)out)[gid] = pack_bf16x2(v.x, v.y);
    }
}

// ------- all 4 weights: W[K][N] fp32 -> Wt[N][K] bf16 (transpose) ----------
__global__ __launch_bounds__(256) void wt_bf16_all(
    const float* __restrict__ Wq, const float* __restrict__ Wk,
    const float* __restrict__ Wv, const float* __restrict__ Wo,
    ushort* __restrict__ Wqkvt, ushort* __restrict__ Wot) {
    __shared__ float tile[32][33];
    const int which = blockIdx.z;
    const float* W = (which == 0) ? Wq : (which == 1) ? Wk : (which == 2) ? Wv : Wo;
    ushort* Wt = (which < 3) ? (Wqkvt + (size_t)which * 1024 * EMB) : Wot;
    const int c0 = blockIdx.x * 32;
    const int r0 = blockIdx.y * 32;
    const int tx = threadIdx.x & 31;
    const int ty = threadIdx.x >> 5;
#pragma unroll
    for (int i = 0; i < 4; ++i)
        tile[ty + i * 8][tx] = W[(size_t)(r0 + ty + i * 8) * EMB + c0 + tx];
    __syncthreads();
#pragma unroll
    for (int i = 0; i < 4; ++i)
        Wt[(size_t)(c0 + ty + i * 8) * EMB + r0 + tx] = bf16_1(tile[tx][ty + i * 8]);
}

// ------- templated bf16 MFMA GEMM: C = A @ Bt^T, TN=128, TM = TMT ----------
// posmode=1 (QKV): col<1024 -> Q=(v+pos)*SCLQ bf16 to QK; col<2048 -> K=v+pos
// bf16 to QK; col>=2048 -> V transposed to Vt[bh][d][s] (packed uint2 in s).
// posmode=0: plain fp32 C[row*N+col].
#define TK 32
#define SCLQ (0.03125f * 1.44269504088896f)

template<int TMT>
__global__ __launch_bounds__(256) void gemm_mfma_t(
    const ushort* __restrict__ A, const ushort* __restrict__ Bt,
    void* __restrict__ Cv, ushort* __restrict__ VtOut,
    const float* __restrict__ pos, int posmode, int N, int K) {
    constexpr int MI = TMT / 32;
    __shared__ ushort As[TMT * TK];
    __shared__ ushort Bs[128 * TK];

    const int t    = threadIdx.x;
    const int lane = t & 63, w = t >> 6;
    const int quad = lane >> 4, l15 = lane & 15;
    const int bm = blockIdx.x * TMT, bn = blockIdx.y * 128;
    const int wm = (w & 1) * (TMT / 2), wn = (w >> 1) * 64;
    const int r0 = t >> 2, kp = (t & 3) * 8;

    f32x4 acc[MI][4];
#pragma unroll
    for (int mi = 0; mi < MI; ++mi)
#pragma unroll
        for (int ni = 0; ni < 4; ++ni)
            acc[mi][ni] = (f32x4){0.f, 0.f, 0.f, 0.f};

    for (int k0 = 0; k0 < K; k0 += TK) {
        __syncthreads();
#pragma unroll
        for (int i = 0; i < TMT / 64; ++i)
            gll16(A + (size_t)(bm + i * 64 + r0) * K + k0 + kp, &As[i * 2048 + t * 8]);
#pragma unroll
        for (int i = 0; i < 2; ++i)
            gll16(Bt + (size_t)(bn + i * 64 + r0) * K + k0 + kp, &Bs[i * 2048 + t * 8]);
        __syncthreads();

        short8 af[MI], bfv[4];
#pragma unroll
        for (int mi = 0; mi < MI; ++mi)
            af[mi] = *(const short8*)&As[(wm + mi * 16 + l15) * TK + quad * 8];
#pragma unroll
        for (int ni = 0; ni < 4; ++ni)
            bfv[ni] = *(const short8*)&Bs[(wn + ni * 16 + l15) * TK + quad * 8];
#pragma unroll
        for (int mi = 0; mi < MI; ++mi)
#pragma unroll
            for (int ni = 0; ni < 4; ++ni)
                acc[mi][ni] = __builtin_amdgcn_mfma_f32_16x16x32_bf16(
                    af[mi], bfv[ni], acc[mi][ni], 0, 0, 0);
    }

#pragma unroll
    for (int mi = 0; mi < MI; ++mi) {
        const int row0 = bm + wm + mi * 16 + quad * 4;
#pragma unroll
        for (int ni = 0; ni < 4; ++ni) {
            const int col = bn + wn + ni * 16 + l15;
            if (!posmode) {
#pragma unroll
                for (int r = 0; r < 4; ++r)
                    ((float*)Cv)[(size_t)(row0 + r) * N + col] = acc[mi][ni][r];
            } else if (col < 2048) {
#pragma unroll
                for (int r = 0; r < 4; ++r) {
                    const int row = row0 + r;
                    const int s   = row & (SEQ - 1);
                    float v = acc[mi][ni][r] + pos[s * DHEAD + (col & 63)];
                    if (col < 1024) v *= SCLQ;
                    ((ushort*)Cv)[(size_t)row * QKS + col] = bf16_1(v);
                }
            } else {
                // V -> Vt[bh][d][s], 4 consecutive s packed
                const int hh = (col >> 6) & 15;
                const int d  = col & 63;
                const int bb = row0 >> 11;
                const int s0 = row0 & (SEQ - 1);
                uint2 u;
                u.x = pack_bf16x2(acc[mi][ni][0], acc[mi][ni][1]);
                u.y = pack_bf16x2(acc[mi][ni][2], acc[mi][ni][3]);
                *(uint2*)&VtOut[((size_t)(bb * 16 + hh) * 64 + d) * SEQ + s0] = u;
            }
        }
    }
}

// ---- MFMA flash attention v6b: paired 32-row q-tiles, 2 waves, LDS K+V ----
// block: q-tiles (p, 63-p) -> uniform 33 K-tile iters; 1024 blocks (4/CU).
// __launch_bounds__(128, 2): min 2 waves/SIMD -> VGPR cap 256 (R10's implicit
// 64-VGPR allocation caused 0.9 GB/dispatch scratch spill traffic).
#define APAD 72

__global__ __launch_bounds__(128, 2) void attn_mfma6(
    const ushort* __restrict__ QK, const ushort* __restrict__ Vt,
    ushort* __restrict__ AOb) {
    __shared__ ushort Ks[64 * APAD];
    __shared__ ushort Vs[64 * APAD];
    __shared__ ushort Ps[2 * 16 * APAD];

    const int p  = blockIdx.x;            // pair 0..31
    const int bh = blockIdx.y;
    const int b  = bh >> 4, hd = bh & 15;
    const int t  = threadIdx.x;
    const int lane = t & 63, w = t >> 6;  // w = 0,1
    const int quad = lane >> 4, l15 = lane & 15;
    ushort* Pw = &Ps[w * 16 * APAD];

    const size_t qkbase = (size_t)b * SEQ * QKS + hd * 64;
    const ushort* Qp  = QK + qkbase;
    const ushort* Kp  = QK + qkbase + 1024;
    const ushort* Vbp = Vt + (size_t)bh * 64 * SEQ;

    const int sr = t >> 1;                // staging row 0..63
    const int sc = (t & 1) * 32;          // 0 or 32 (ushorts)

#pragma unroll
    for (int ph = 0; ph < 2; ++ph) {
        const int qt = ph ? (63 - p) : p; // 32-row q-tile

        // Q fragments direct from global (pre-scaled by SCLQ in GEMM)
        const ushort* qp = Qp + (size_t)(qt * 32 + w * 16 + l15) * QKS + quad * 8;
        const short8 bq0 = *(const short8*)qp;
        const short8 bq1 = *(const short8*)(qp + 32);

        f32x4 acc_o[4];
#pragma unroll
        for (int nd = 0; nd < 4; ++nd) acc_o[nd] = (f32x4){0.f, 0.f, 0.f, 0.f};
        float m_l = -3.0e38f, l_l = 0.f;  // state for q = qt*32 + w*16 + l15
        const int qrow = qt * 32 + w * 16 + l15;
        const int ktl  = qt >> 1;         // last (diagonal) 64-key tile

        // prefetch kt=0
        uint4 ka[4], va[4];
#pragma unroll
        for (int j = 0; j < 4; ++j) {
            ka[j] = *(const uint4*)(Kp + (size_t)sr * QKS + sc + j * 8);
            va[j] = *(const uint4*)(Vbp + (size_t)sr * SEQ + sc + j * 8);
        }

        for (int kt = 0; kt <= ktl; ++kt) {
            __syncthreads();
#pragma unroll
            for (int j = 0; j < 4; ++j) {
                *(uint4*)&Ks[sr * APAD + sc + j * 8] = ka[j];
                *(uint4*)&Vs[sr * APAD + sc + j * 8] = va[j];
            }
            const int ktn = (kt < ktl) ? kt + 1 : ktl;
#pragma unroll
            for (int j = 0; j < 4; ++j) {
                ka[j] = *(const uint4*)(Kp + (size_t)(ktn * 64 + sr) * QKS + sc + j * 8);
                va[j] = *(const uint4*)(Vbp + (size_t)sr * SEQ + ktn * 64 + sc + j * 8);
            }
            __syncthreads();

            // ---- S^T = K Q^T : lane holds (key=kg*16+quad*4+r, q=l15) ----
            float sv[4][4];
            float mloc = m_l;
            const bool diag = (kt == ktl);
#pragma unroll
            for (int kg = 0; kg < 4; ++kg) {
                const short8 ak0 = *(const short8*)&Ks[(kg * 16 + l15) * APAD + quad * 8];
                const short8 ak1 = *(const short8*)&Ks[(kg * 16 + l15) * APAD + 32 + quad * 8];
                f32x4 a = (f32x4){0.f, 0.f, 0.f, 0.f};
                a = __builtin_amdgcn_mfma_f32_16x16x32_bf16(ak0, bq0, a, 0, 0, 0);
                a = __builtin_amdgcn_mfma_f32_16x16x32_bf16(ak1, bq1, a, 0, 0, 0);
                if (diag) {
                    const int keyb = kt * 64 + kg * 16 + quad * 4;
#pragma unroll
                    for (int r = 0; r < 4; ++r) {
                        float v = (keyb + r > qrow) ? -3.0e38f : a[r];
                        sv[kg][r] = v;
                        mloc = fmaxf(mloc, v);
                    }
                } else {
#pragma unroll
                    for (int r = 0; r < 4; ++r) {
                        sv[kg][r] = a[r];
                        mloc = fmaxf(mloc, a[r]);
                    }
                }
            }
            mloc = fmaxf(mloc, __shfl_xor(mloc, 16, 64));
            mloc = fmaxf(mloc, __shfl_xor(mloc, 32, 64));
            const float alpha = exp2_fast(m_l - mloc);
            m_l = mloc;
            float rs = 0.f;
#pragma unroll
            for (int kg = 0; kg < 4; ++kg)
#pragma unroll
                for (int r = 0; r < 4; ++r) {
                    float pv = exp2_fast(sv[kg][r] - mloc);
                    sv[kg][r] = pv;
                    rs += pv;
                }
            rs += __shfl_xor(rs, 16, 64);
            rs += __shfl_xor(rs, 32, 64);
            l_l = l_l * alpha + rs;

            float av[4];
#pragma unroll
            for (int r = 0; r < 4; ++r) av[r] = __shfl(alpha, quad * 4 + r, 64);
#pragma unroll
            for (int nd = 0; nd < 4; ++nd)
#pragma unroll
                for (int r = 0; r < 4; ++r) acc_o[nd][r] *= av[r];

            // ---- P: C-layout -> A-layout via private per-wave LDS ----
#pragma unroll
            for (int kg = 0; kg < 4; ++kg) {
                uint2 u;
                u.x = pack_bf16x2(sv[kg][0], sv[kg][1]);
                u.y = pack_bf16x2(sv[kg][2], sv[kg][3]);
                *(uint2*)&Pw[l15 * APAD + kg * 16 + quad * 4] = u;
            }
            const short8 pa0 = *(const short8*)&Pw[l15 * APAD + quad * 8];
            const short8 pa1 = *(const short8*)&Pw[l15 * APAD + 32 + quad * 8];
#pragma unroll
            for (int nd = 0; nd < 4; ++nd) {
                const short8 bv0 = *(const short8*)&Vs[(nd * 16 + l15) * APAD + quad * 8];
                const short8 bv1 = *(const short8*)&Vs[(nd * 16 + l15) * APAD + 32 + quad * 8];
                acc_o[nd] = __builtin_amdgcn_mfma_f32_16x16x32_bf16(pa0, bv0, acc_o[nd], 0, 0, 0);
                acc_o[nd] = __builtin_amdgcn_mfma_f32_16x16x32_bf16(pa1, bv1, acc_o[nd], 0, 0, 0);
            }
        }

        // ---- epilogue ----
        float linv[4];
#pragma unroll
        for (int r = 0; r < 4; ++r) linv[r] = 1.0f / __shfl(l_l, quad * 4 + r, 64);
#pragma unroll
        for (int nd = 0; nd < 4; ++nd)
#pragma unroll
            for (int r = 0; r < 4; ++r) {
                const int row = qt * 32 + w * 16 + quad * 4 + r;
                AOb[(size_t)(b * SEQ + row) * EMB + hd * 64 + nd * 16 + l15] =
                    bf16_1(acc_o[nd][r] * linv[r]);
            }
    }
}

// ---------------- fp32 fallback GEMM ----------------
#define BM 64
#define BN 64
#define BK 16

__global__ __launch_bounds__(256) void gemm_f32(
    const float* __restrict__ A, const float* __restrict__ B,
    float* __restrict__ C, const float* __restrict__ pos, int addpos,
    int M, int N, int K) {
    __shared__ float As[BK][BM];
    __shared__ float Bs[BK][BN];
    const int tid = threadIdx.x;
    const int bm  = blockIdx.x * BM;
    const int bn  = blockIdx.y * BN;
    const int tx  = tid & 15;
    const int ty  = tid >> 4;
    const int arow = tid >> 2;
    const int acol = (tid & 3) << 2;
    const int brow = tid >> 4;
    const int bcol = (tid & 15) << 2;
    float acc[4][4] = {{0.f}};
    const float* Aptr = A + (size_t)(bm + arow) * K + acol;
    const float* Bptr = B + (size_t)brow * N + bn + bcol;
    for (int k0 = 0; k0 < K; k0 += BK) {
        float4 av = *(const float4*)(Aptr + k0);
        float4 bv = *(const float4*)(Bptr + (size_t)k0 * N);
        __syncthreads();
        As[acol + 0][arow] = av.x;
        As[acol + 1][arow] = av.y;
        As[acol + 2][arow] = av.z;
        As[acol + 3][arow] = av.w;
        *(float4*)&Bs[brow][bcol] = bv;
        __syncthreads();
#pragma unroll
        for (int kk = 0; kk < BK; ++kk) {
            float4 a = *(const float4*)&As[kk][ty << 2];
            float4 b = *(const float4*)&Bs[kk][tx << 2];
            float aa[4] = {a.x, a.y, a.z, a.w};
            float bb[4] = {b.x, b.y, b.z, b.w};
#pragma unroll
            for (int i = 0; i < 4; ++i)
#pragma unroll
                for (int j = 0; j < 4; ++j)
                    acc[i][j] += aa[i] * bb[j];
        }
    }
#pragma unroll
    for (int i = 0; i < 4; ++i) {
        int m = bm + (ty << 2) + i;
        int n = bn + (tx << 2);
        float4 v = make_float4(acc[i][0], acc[i][1], acc[i][2], acc[i][3]);
        if (addpos) {
            int s = m & (SEQ - 1);
            int d = n & (DHEAD - 1);
            float4 p = *(const float4*)&pos[s * DHEAD + d];
            v.x += p.x; v.y += p.y; v.z += p.z; v.w += p.w;
        }
        *(float4*)&C[(size_t)m * N + n] = v;
    }
}

// ---------------- fp32 fallback attention ----------------
#define QT 128
#define KT 32
__global__ __launch_bounds__(QT) void attn_fwd(
    const float* __restrict__ Q, const float* __restrict__ Kg,
    const float* __restrict__ V, float* __restrict__ O) {
    __shared__ float Ks[KT][DHEAD];
    __shared__ float Vs[KT][DHEAD];
    const int t    = threadIdx.x;
    const int q0   = blockIdx.x * QT;
    const int bh   = blockIdx.y;
    const int b    = bh >> 4;
    const int h    = bh & 15;
    const int qrow = q0 + t;
    const size_t base = (size_t)b * SEQ * EMB + (size_t)h * DHEAD;
    float4 q4[16], o4[16];
#pragma unroll
    for (int i = 0; i < 16; ++i) {
        q4[i] = *(const float4*)&Q[base + (size_t)qrow * EMB + i * 4];
        o4[i] = make_float4(0.f, 0.f, 0.f, 0.f);
    }
    float m_i = -3.0e38f, l_i = 0.0f;
    const float scale = 0.03125f;
    const int kend = q0 + QT;
    for (int k0 = 0; k0 < kend; k0 += KT) {
        __syncthreads();
#pragma unroll
        for (int i = 0; i < 4; ++i) {
            int idx = t + i * QT;
            int r = idx >> 4;
            int c = (idx & 15) << 2;
            *(float4*)&Ks[r][c] = *(const float4*)&Kg[base + (size_t)(k0 + r) * EMB + c];
            *(float4*)&Vs[r][c] = *(const float4*)&V [base + (size_t)(k0 + r) * EMB + c];
        }
        __syncthreads();
        float sv[KT];
        float mt = m_i;
#pragma unroll
        for (int j = 0; j < KT; ++j) {
            const float4* kr = (const float4*)Ks[j];
            float dot = 0.f;
#pragma unroll
            for (int dd = 0; dd < 16; ++dd) {
                float4 kv = kr[dd];
                dot += q4[dd].x * kv.x + q4[dd].y * kv.y +
                       q4[dd].z * kv.z + q4[dd].w * kv.w;
            }
            sv[j] = (k0 + j <= qrow) ? dot * scale : -3.0e38f;
            mt = fmaxf(mt, sv[j]);
        }
        float corr = __expf(m_i - mt);
        l_i *= corr;
#pragma unroll
        for (int i = 0; i < 16; ++i) {
            o4[i].x *= corr; o4[i].y *= corr; o4[i].z *= corr; o4[i].w *= corr;
        }
#pragma unroll
        for (int j = 0; j < KT; ++j) {
            float pp = __expf(sv[j] - mt);
            l_i += pp;
            const float4* vr = (const float4*)Vs[j];
#pragma unroll
            for (int dd = 0; dd < 16; ++dd) {
                float4 vv = vr[dd];
                o4[dd].x += pp * vv.x; o4[dd].y += pp * vv.y;
                o4[dd].z += pp * vv.z; o4[dd].w += pp * vv.w;
            }
        }
        m_i = mt;
    }
    float inv = 1.0f / l_i;
#pragma unroll
    for (int i = 0; i < 16; ++i) {
        float4 v = o4[i];
        v.x *= inv; v.y *= inv; v.z *= inv; v.w *= inv;
        *(float4*)&O[base + (size_t)qrow * EMB + i * 4] = v;
    }
}

// ---------------- launch ----------------
extern "C" void kernel_launch(void* const* d_in, const int* in_sizes, int n_in,
                              void* d_out, int out_size, void* d_ws, size_t ws_size,
                              hipStream_t stream) {
    const float* x  = (const float*)d_in[0];
    const float* Wq = (const float*)d_in[1];
    const float* Wk = (const float*)d_in[2];
    const float* Wv = (const float*)d_in[3];
    const float* Wo = (const float*)d_in[4];
    float* out = (float*)d_out;

    char* ws = (char*)d_ws;
    size_t off = 0;
    float*  pos   = (float*)(ws + off);  off += (size_t)SEQ * DHEAD * 4;
    ushort* xb    = (ushort*)(ws + off); off += (size_t)MROWS * EMB * 2;
    ushort* Wqkvt = (ushort*)(ws + off); off += (size_t)3072 * EMB * 2;
    ushort* Wot   = (ushort*)(ws + off); off += (size_t)EMB * EMB * 2;
    ushort* QKb   = (ushort*)(ws + off); off += (size_t)MROWS * QKS * 2;
    ushort* Vtp   = (ushort*)(ws + off); off += (size_t)MROWS * EMB * 2;
    ushort* AOb   = (ushort*)(ws + off); off += (size_t)MROWS * EMB * 2;
    const bool use_bf16 = off <= ws_size;

    const int M = MROWS, K = EMB;

    pos_init<<<SEQ, DHEAD, 0, stream>>>(pos);

    if (use_bf16) {
        const int n2 = MROWS * EMB / 2;
        cvt_bf16<<<n2 / 256, 256, 0, stream>>>(x, xb, n2);
        wt_bf16_all<<<dim3(EMB / 32, EMB / 32, 4), 256, 0, stream>>>(
            Wq, Wk, Wv, Wo, Wqkvt, Wot);

        // fused QKV projection: Q/K -> QKb (stride 2048, +pos, Q*scl),
        // V -> Vtp transposed [bh][d][s]
        gemm_mfma_t<128><<<dim3(M / 128, 3072 / 128), 256, 0, stream>>>(
            xb, Wqkvt, QKb, Vtp, pos, 1, 3072, K);

        attn_mfma6<<<dim3(32, BATCH * NHEAD), 128, 0, stream>>>(QKb, Vtp, AOb);

        // Wo GEMM: TM=64 -> 512 blocks (2/CU)
        gemm_mfma_t<64><<<dim3(M / 64, EMB / 128), 256, 0, stream>>>(
            AOb, Wot, out, nullptr, pos, 0, EMB, K);
    } else {
        // fp32 fallback
        size_t f = 0;
        float* posf = (float*)(ws + f); f += (size_t)SEQ * DHEAD * 4;
        float* Qb = (float*)(ws + f); f += (size_t)MROWS * EMB * 4;
        float* Kb = (float*)(ws + f); f += (size_t)MROWS * EMB * 4;
        float* Vb = (float*)(ws + f); f += (size_t)MROWS * EMB * 4;
        float* AO = (float*)(ws + f);
        dim3 g(M / BM, EMB / BN);
        gemm_f32<<<g, 256, 0, stream>>>(x, Wq, Qb, posf, 1, M, EMB, K);
        gemm_f32<<<g, 256, 0, stream>>>(x, Wk, Kb, posf, 1, M, EMB, K);
        gemm_f32<<<g, 256, 0, stream>>>(x, Wv, Vb, posf, 0, M, EMB, K);
        attn_fwd<<<dim3(SEQ / QT, BATCH * NHEAD), QT, 0, stream>>>(Qb, Kb, Vb, AO);
        gemm_f32<<<g, 256, 0, stream>>>(AO, Wo, out, posf, 0, M, EMB, K);
    }
}

// Round 12
// 200.835 us; speedup vs baseline: 1.9072x; 1.8821x over previous
//
#include <hip/hip_runtime.h>
#include <math.h>

#define BATCH 2
#define SEQ   2048
#define EMB   1024
#define NHEAD 16
#define DHEAD 64
#define MROWS (BATCH*SEQ)
#define QKS   2048          // Q|K packed row stride (Q cols 0..1023, K 1024..2047)

typedef unsigned int  uint;
typedef unsigned short ushort;
typedef __attribute__((ext_vector_type(8))) short short8;
typedef __attribute__((ext_vector_type(4))) float f32x4;

__device__ __forceinline__ float exp2_fast(float x) {
    return __builtin_amdgcn_exp2f(x);
}

// ---------------- positional encoding table ----------------
__global__ void pos_init(float* __restrict__ pos) {
    int s = blockIdx.x;
    int d = threadIdx.x;              // 0..63
    int i = d >> 1;
    float expo  = (float)(2 * i) / (float)DHEAD;
    float scale = 1.0f / (powf(10000.0f, expo) + 1.1920928955078125e-07f);
    float ang   = (float)s * scale;
    pos[s * DHEAD + d] = (d & 1) ? cosf(ang) : sinf(ang);
}

// ---------------- bf16 helpers ----------------
__device__ __forceinline__ uint pack_bf16x2(float a, float b) {
    union { float f; uint u; } x, y;
    x.f = a; y.f = b;
    uint ua = x.u + 0x7fffu + ((x.u >> 16) & 1u);   // RNE
    uint ub = y.u + 0x7fffu + ((y.u >> 16) & 1u);
    return (ua >> 16) | (ub & 0xffff0000u);
}
__device__ __forceinline__ ushort bf16_1(float a) {
    union { float f; uint u; } x; x.f = a;
    return (ushort)((x.u + 0x7fffu + ((x.u >> 16) & 1u)) >> 16);
}

// async global->LDS, 16B per lane
__device__ __forceinline__ void gll16(const ushort* g, ushort* l) {
    __builtin_amdgcn_global_load_lds(
        (const __attribute__((address_space(1))) uint*)g,
        (__attribute__((address_space(3))) uint*)l, 16, 0, 0);
}

// ---------------- fp32 -> bf16 (rowmajor) ----------------
__global__ __launch_bounds__(256) void cvt_bf16(
    const float* __restrict__ in, ushort* __restrict__ out, int n2) {
    int gid = blockIdx.x * 256 + threadIdx.x;
    if (gid < n2) {
        float2 v = ((const float2*)in)[gid];
        ((uint*)out)[gid] = pack_bf16x2(v.x, v.y);
    }
}

// ------- all 4 weights: W[K][N] fp32 -> Wt[N][K] bf16 (transpose) ----------
__global__ __launch_bounds__(256) void wt_bf16_all(
    const float* __restrict__ Wq, const float* __restrict__ Wk,
    const float* __restrict__ Wv, const float* __restrict__ Wo,
    ushort* __restrict__ Wqkvt, ushort* __restrict__ Wot) {
    __shared__ float tile[32][33];
    const int which = blockIdx.z;
    const float* W = (which == 0) ? Wq : (which == 1) ? Wk : (which == 2) ? Wv : Wo;
    ushort* Wt = (which < 3) ? (Wqkvt + (size_t)which * 1024 * EMB) : Wot;
    const int c0 = blockIdx.x * 32;
    const int r0 = blockIdx.y * 32;
    const int tx = threadIdx.x & 31;
    const int ty = threadIdx.x >> 5;
#pragma unroll
    for (int i = 0; i < 4; ++i)
        tile[ty + i * 8][tx] = W[(size_t)(r0 + ty + i * 8) * EMB + c0 + tx];
    __syncthreads();
#pragma unroll
    for (int i = 0; i < 4; ++i)
        Wt[(size_t)(c0 + ty + i * 8) * EMB + r0 + tx] = bf16_1(tile[tx][ty + i * 8]);
}

// ------- templated bf16 MFMA GEMM: C = A @ Bt^T, TN=128, TM = TMT ----------
// posmode=1 (QKV): col<1024 -> Q=(v+pos)*SCLQ bf16 to QK; col<2048 -> K=v+pos
// bf16 to QK; col>=2048 -> V transposed to Vt[bh][d][s] (packed uint2 in s).
// posmode=0: plain fp32 C[row*N+col].
#define TK 32
#define SCLQ (0.03125f * 1.44269504088896f)

template<int TMT>
__global__ __launch_bounds__(256) void gemm_mfma_t(
    const ushort* __restrict__ A, const ushort* __restrict__ Bt,
    void* __restrict__ Cv, ushort* __restrict__ VtOut,
    const float* __restrict__ pos, int posmode, int N, int K) {
    constexpr int MI = TMT / 32;
    __shared__ ushort As[TMT * TK];
    __shared__ ushort Bs[128 * TK];

    const int t    = threadIdx.x;
    const int lane = t & 63, w = t >> 6;
    const int quad = lane >> 4, l15 = lane & 15;
    const int bm = blockIdx.x * TMT, bn = blockIdx.y * 128;
    const int wm = (w & 1) * (TMT / 2), wn = (w >> 1) * 64;
    const int r0 = t >> 2, kp = (t & 3) * 8;

    f32x4 acc[MI][4];
#pragma unroll
    for (int mi = 0; mi < MI; ++mi)
#pragma unroll
        for (int ni = 0; ni < 4; ++ni)
            acc[mi][ni] = (f32x4){0.f, 0.f, 0.f, 0.f};

    for (int k0 = 0; k0 < K; k0 += TK) {
        __syncthreads();
#pragma unroll
        for (int i = 0; i < TMT / 64; ++i)
            gll16(A + (size_t)(bm + i * 64 + r0) * K + k0 + kp, &As[i * 2048 + t * 8]);
#pragma unroll
        for (int i = 0; i < 2; ++i)
            gll16(Bt + (size_t)(bn + i * 64 + r0) * K + k0 + kp, &Bs[i * 2048 + t * 8]);
        __syncthreads();

        short8 af[MI], bfv[4];
#pragma unroll
        for (int mi = 0; mi < MI; ++mi)
            af[mi] = *(const short8*)&As[(wm + mi * 16 + l15) * TK + quad * 8];
#pragma unroll
        for (int ni = 0; ni < 4; ++ni)
            bfv[ni] = *(const short8*)&Bs[(wn + ni * 16 + l15) * TK + quad * 8];
#pragma unroll
        for (int mi = 0; mi < MI; ++mi)
#pragma unroll
            for (int ni = 0; ni < 4; ++ni)
                acc[mi][ni] = __builtin_amdgcn_mfma_f32_16x16x32_bf16(
                    af[mi], bfv[ni], acc[mi][ni], 0, 0, 0);
    }

#pragma unroll
    for (int mi = 0; mi < MI; ++mi) {
        const int row0 = bm + wm + mi * 16 + quad * 4;
#pragma unroll
        for (int ni = 0; ni < 4; ++ni) {
            const int col = bn + wn + ni * 16 + l15;
            if (!posmode) {
#pragma unroll
                for (int r = 0; r < 4; ++r)
                    ((float*)Cv)[(size_t)(row0 + r) * N + col] = acc[mi][ni][r];
            } else if (col < 2048) {
#pragma unroll
                for (int r = 0; r < 4; ++r) {
                    const int row = row0 + r;
                    const int s   = row & (SEQ - 1);
                    float v = acc[mi][ni][r] + pos[s * DHEAD + (col & 63)];
                    if (col < 1024) v *= SCLQ;
                    ((ushort*)Cv)[(size_t)row * QKS + col] = bf16_1(v);
                }
            } else {
                // V -> Vt[bh][d][s], 4 consecutive s packed
                const int hh = (col >> 6) & 15;
                const int d  = col & 63;
                const int bb = row0 >> 11;
                const int s0 = row0 & (SEQ - 1);
                uint2 u;
                u.x = pack_bf16x2(acc[mi][ni][0], acc[mi][ni][1]);
                u.y = pack_bf16x2(acc[mi][ni][2], acc[mi][ni][3]);
                *(uint2*)&VtOut[((size_t)(bb * 16 + hh) * 64 + d) * SEQ + s0] = u;
            }
        }
    }
}

// -- MFMA flash attention v7 = R7-proven shape (named prefetch scalars) -----
// block: 256 thr = 4 waves; q-tiles (pair, 31-pair) 64 rows each; wave owns
// 16 q-rows. K/V staged via named uint4 prefetch regs -> padded LDS; Q frags
// direct from global (pre-scaled); P per-wave private LDS region.
#define LDP 72   // padded LDS row stride in ushorts

__global__ __launch_bounds__(256) void attn_mfma7(
    const ushort* __restrict__ QK, const ushort* __restrict__ Vt,
    ushort* __restrict__ AOb) {
    __shared__ ushort Ks[64 * LDP];
    __shared__ ushort Vs[64 * LDP];
    __shared__ ushort Ps[64 * LDP];

    const int pair = blockIdx.x;          // 0..15
    const int bh   = blockIdx.y;
    const int b    = bh >> 4, hd = bh & 15;
    const int t    = threadIdx.x;
    const int lane = t & 63, w = t >> 6;
    const int quad = lane >> 4, l15 = lane & 15;
    const int wrow = w * 16;
    const int sr = t >> 2;                // staging row 0..63
    const int sc = (t & 3) * 16;          // 0,16,32,48

    const size_t qkbase = (size_t)b * SEQ * QKS + hd * 64;
    const ushort* kpb = QK + qkbase + 1024 + (size_t)sr * QKS + sc;  // + kt*64*QKS
    const ushort* vpb = Vt + ((size_t)bh * 64 + sr) * SEQ;           // + kt*64 + sc

#pragma unroll
    for (int ph = 0; ph < 2; ++ph) {
        const int qt = ph ? (31 - pair) : pair;

        // Q fragments directly from global (pre-scaled by SCLQ in GEMM)
        const ushort* qp = QK + qkbase + (size_t)(qt * 64 + wrow + l15) * QKS + quad * 8;
        const short8 aq0 = *(const short8*)qp;
        const short8 aq1 = *(const short8*)(qp + 32);

        // prefetch kt = 0 (named scalars -- promoted to VGPRs, R7-proven)
        uint4 ka = *(const uint4*)kpb;
        uint4 kb = *(const uint4*)(kpb + 8);
        uint4 va = *(const uint4*)(vpb + sc);
        uint4 vb = *(const uint4*)(vpb + sc + 8);

        f32x4 acc_o[4];
#pragma unroll
        for (int nd = 0; nd < 4; ++nd) acc_o[nd] = (f32x4){0.f, 0.f, 0.f, 0.f};
        float m_l = -3.0e38f, l_l = 0.f;          // softmax state for q = l15
        const int qrow_g = qt * 64 + wrow + l15;

        for (int kt = 0; kt <= qt; ++kt) {
            __syncthreads();
            *(uint4*)&Ks[sr * LDP + sc]     = ka;
            *(uint4*)&Ks[sr * LDP + sc + 8] = kb;
            *(uint4*)&Vs[sr * LDP + sc]     = va;
            *(uint4*)&Vs[sr * LDP + sc + 8] = vb;
            // prefetch next tile (overlaps this tile's compute)
            const int ktn = (kt < qt) ? kt + 1 : qt;
            ka = *(const uint4*)(kpb + (size_t)ktn * 64 * QKS);
            kb = *(const uint4*)(kpb + (size_t)ktn * 64 * QKS + 8);
            va = *(const uint4*)(vpb + ktn * 64 + sc);
            vb = *(const uint4*)(vpb + ktn * 64 + sc + 8);
            __syncthreads();

            // ---- S^T = K Q^T : lane holds (key=kg*16+quad*4+r, q=l15) ----
            float sv[4][4];
            float mloc = m_l;
            const bool diag = (kt == qt);
#pragma unroll
            for (int kg = 0; kg < 4; ++kg) {
                const short8 ak0 = *(const short8*)&Ks[(kg * 16 + l15) * LDP + quad * 8];
                const short8 ak1 = *(const short8*)&Ks[(kg * 16 + l15) * LDP + 32 + quad * 8];
                f32x4 a = (f32x4){0.f, 0.f, 0.f, 0.f};
                a = __builtin_amdgcn_mfma_f32_16x16x32_bf16(ak0, aq0, a, 0, 0, 0);
                a = __builtin_amdgcn_mfma_f32_16x16x32_bf16(ak1, aq1, a, 0, 0, 0);
                const int keyb = kt * 64 + kg * 16 + quad * 4;
#pragma unroll
                for (int r = 0; r < 4; ++r) {
                    float v = a[r];                 // already in log2 domain
                    if (diag && (keyb + r > qrow_g)) v = -3.0e38f;
                    sv[kg][r] = v;
                    mloc = fmaxf(mloc, v);
                }
            }
            mloc = fmaxf(mloc, __shfl_xor(mloc, 16, 64));
            mloc = fmaxf(mloc, __shfl_xor(mloc, 32, 64));
            const float alpha = exp2_fast(m_l - mloc);
            m_l = mloc;
            float rs = 0.f;
#pragma unroll
            for (int kg = 0; kg < 4; ++kg)
#pragma unroll
                for (int r = 0; r < 4; ++r) {
                    float p = exp2_fast(sv[kg][r] - mloc);
                    sv[kg][r] = p;
                    rs += p;
                }
            rs += __shfl_xor(rs, 16, 64);
            rs += __shfl_xor(rs, 32, 64);
            l_l = l_l * alpha + rs;

            // broadcast alpha to accumulator layout (row q = quad*4+r)
            float av[4];
#pragma unroll
            for (int r = 0; r < 4; ++r) av[r] = __shfl(alpha, quad * 4 + r, 64);
#pragma unroll
            for (int nd = 0; nd < 4; ++nd)
#pragma unroll
                for (int r = 0; r < 4; ++r) acc_o[nd][r] *= av[r];

            // ---- P[q][key] write: 4 x b64 per lane (per-wave region) ----
            ushort* Pw = &Ps[wrow * LDP];
#pragma unroll
            for (int kg = 0; kg < 4; ++kg) {
                uint2 u;
                u.x = pack_bf16x2(sv[kg][0], sv[kg][1]);
                u.y = pack_bf16x2(sv[kg][2], sv[kg][3]);
                *(uint2*)&Pw[l15 * LDP + kg * 16 + quad * 4] = u;
            }
            const short8 pa0 = *(const short8*)&Pw[l15 * LDP + quad * 8];
            const short8 pa1 = *(const short8*)&Pw[l15 * LDP + 32 + quad * 8];
#pragma unroll
            for (int nd = 0; nd < 4; ++nd) {
                const short8 bv0 = *(const short8*)&Vs[(nd * 16 + l15) * LDP + quad * 8];
                const short8 bv1 = *(const short8*)&Vs[(nd * 16 + l15) * LDP + 32 + quad * 8];
                acc_o[nd] = __builtin_amdgcn_mfma_f32_16x16x32_bf16(pa0, bv0, acc_o[nd], 0, 0, 0);
                acc_o[nd] = __builtin_amdgcn_mfma_f32_16x16x32_bf16(pa1, bv1, acc_o[nd], 0, 0, 0);
            }
        }

        // ---- epilogue ----
        float linv[4];
#pragma unroll
        for (int r = 0; r < 4; ++r) linv[r] = 1.0f / __shfl(l_l, quad * 4 + r, 64);
#pragma unroll
        for (int nd = 0; nd < 4; ++nd)
#pragma unroll
            for (int r = 0; r < 4; ++r) {
                const int row = qt * 64 + wrow + quad * 4 + r;
                AOb[(size_t)(b * SEQ + row) * EMB + hd * 64 + nd * 16 + l15] =
                    bf16_1(acc_o[nd][r] * linv[r]);
            }
    }
}

// ---------------- fp32 fallback GEMM ----------------
#define BM 64
#define BN 64
#define BK 16

__global__ __launch_bounds__(256) void gemm_f32(
    const float* __restrict__ A, const float* __restrict__ B,
    float* __restrict__ C, const float* __restrict__ pos, int addpos,
    int M, int N, int K) {
    __shared__ float As[BK][BM];
    __shared__ float Bs[BK][BN];
    const int tid = threadIdx.x;
    const int bm  = blockIdx.x * BM;
    const int bn  = blockIdx.y * BN;
    const int tx  = tid & 15;
    const int ty  = tid >> 4;
    const int arow = tid >> 2;
    const int acol = (tid & 3) << 2;
    const int brow = tid >> 4;
    const int bcol = (tid & 15) << 2;
    float acc[4][4] = {{0.f}};
    const float* Aptr = A + (size_t)(bm + arow) * K + acol;
    const float* Bptr = B + (size_t)brow * N + bn + bcol;
    for (int k0 = 0; k0 < K; k0 += BK) {
        float4 av = *(const float4*)(Aptr + k0);
        float4 bv = *(const float4*)(Bptr + (size_t)k0 * N);
        __syncthreads();
        As[acol + 0][arow] = av.x;
        As[acol + 1][arow] = av.y;
        As[acol + 2][arow] = av.z;
        As[acol + 3][arow] = av.w;
        *(float4*)&Bs[brow][bcol] = bv;
        __syncthreads();
#pragma unroll
        for (int kk = 0; kk < BK; ++kk) {
            float4 a = *(const float4*)&As[kk][ty << 2];
            float4 b = *(const float4*)&Bs[kk][tx << 2];
            float aa[4] = {a.x, a.y, a.z, a.w};
            float bb[4] = {b.x, b.y, b.z, b.w};
#pragma unroll
            for (int i = 0; i < 4; ++i)
#pragma unroll
                for (int j = 0; j < 4; ++j)
                    acc[i][j] += aa[i] * bb[j];
        }
    }
#pragma unroll
    for (int i = 0; i < 4; ++i) {
        int m = bm + (ty << 2) + i;
        int n = bn + (tx << 2);
        float4 v = make_float4(acc[i][0], acc[i][1], acc[i][2], acc[i][3]);
        if (addpos) {
            int s = m & (SEQ - 1);
            int d = n & (DHEAD - 1);
            float4 p = *(const float4*)&pos[s * DHEAD + d];
            v.x += p.x; v.y += p.y; v.z += p.z; v.w += p.w;
        }
        *(float4*)&C[(size_t)m * N + n] = v;
    }
}

// ---------------- fp32 fallback attention ----------------
#define QT 128
#define KT 32
__global__ __launch_bounds__(QT) void attn_fwd(
    const float* __restrict__ Q, const float* __restrict__ Kg,
    const float* __restrict__ V, float* __restrict__ O) {
    __shared__ float Ks[KT][DHEAD];
    __shared__ float Vs[KT][DHEAD];
    const int t    = threadIdx.x;
    const int q0   = blockIdx.x * QT;
    const int bh   = blockIdx.y;
    const int b    = bh >> 4;
    const int h    = bh & 15;
    const int qrow = q0 + t;
    const size_t base = (size_t)b * SEQ * EMB + (size_t)h * DHEAD;
    float4 q4[16], o4[16];
#pragma unroll
    for (int i = 0; i < 16; ++i) {
        q4[i] = *(const float4*)&Q[base + (size_t)qrow * EMB + i * 4];
        o4[i] = make_float4(0.f, 0.f, 0.f, 0.f);
    }
    float m_i = -3.0e38f, l_i = 0.0f;
    const float scale = 0.03125f;
    const int kend = q0 + QT;
    for (int k0 = 0; k0 < kend; k0 += KT) {
        __syncthreads();
#pragma unroll
        for (int i = 0; i < 4; ++i) {
            int idx = t + i * QT;
            int r = idx >> 4;
            int c = (idx & 15) << 2;
            *(float4*)&Ks[r][c] = *(const float4*)&Kg[base + (size_t)(k0 + r) * EMB + c];
            *(float4*)&Vs[r][c] = *(const float4*)&V [base + (size_t)(k0 + r) * EMB + c];
        }
        __syncthreads();
        float sv[KT];
        float mt = m_i;
#pragma unroll
        for (int j = 0; j < KT; ++j) {
            const float4* kr = (const float4*)Ks[j];
            float dot = 0.f;
#pragma unroll
            for (int dd = 0; dd < 16; ++dd) {
                float4 kv = kr[dd];
                dot += q4[dd].x * kv.x + q4[dd].y * kv.y +
                       q4[dd].z * kv.z + q4[dd].w * kv.w;
            }
            sv[j] = (k0 + j <= qrow) ? dot * scale : -3.0e38f;
            mt = fmaxf(mt, sv[j]);
        }
        float corr = __expf(m_i - mt);
        l_i *= corr;
#pragma unroll
        for (int i = 0; i < 16; ++i) {
            o4[i].x *= corr; o4[i].y *= corr; o4[i].z *= corr; o4[i].w *= corr;
        }
#pragma unroll
        for (int j = 0; j < KT; ++j) {
            float pp = __expf(sv[j] - mt);
            l_i += pp;
            const float4* vr = (const float4*)Vs[j];
#pragma unroll
            for (int dd = 0; dd < 16; ++dd) {
                float4 vv = vr[dd];
                o4[dd].x += pp * vv.x; o4[dd].y += pp * vv.y;
                o4[dd].z += pp * vv.z; o4[dd].w += pp * vv.w;
            }
        }
        m_i = mt;
    }
    float inv = 1.0f / l_i;
#pragma unroll
    for (int i = 0; i < 16; ++i) {
        float4 v = o4[i];
        v.x *= inv; v.y *= inv; v.z *= inv; v.w *= inv;
        *(float4*)&O[base + (size_t)qrow * EMB + i * 4] = v;
    }
}

// ---------------- launch ----------------
extern "C" void kernel_launch(void* const* d_in, const int* in_sizes, int n_in,
                              void* d_out, int out_size, void* d_ws, size_t ws_size,
                              hipStream_t stream) {
    const float* x  = (const float*)d_in[0];
    const float* Wq = (const float*)d_in[1];
    const float* Wk = (const float*)d_in[2];
    const float* Wv = (const float*)d_in[3];
    const float* Wo = (const float*)d_in[4];
    float* out = (float*)d_out;

    char* ws = (char*)d_ws;
    size_t off = 0;
    float*  pos   = (float*)(ws + off);  off += (size_t)SEQ * DHEAD * 4;
    ushort* xb    = (ushort*)(ws + off); off += (size_t)MROWS * EMB * 2;
    ushort* Wqkvt = (ushort*)(ws + off); off += (size_t)3072 * EMB * 2;
    ushort* Wot   = (ushort*)(ws + off); off += (size_t)EMB * EMB * 2;
    ushort* QKb   = (ushort*)(ws + off); off += (size_t)MROWS * QKS * 2;
    ushort* Vtp   = (ushort*)(ws + off); off += (size_t)MROWS * EMB * 2;
    ushort* AOb   = (ushort*)(ws + off); off += (size_t)MROWS * EMB * 2;
    const bool use_bf16 = off <= ws_size;

    const int M = MROWS, K = EMB;

    pos_init<<<SEQ, DHEAD, 0, stream>>>(pos);

    if (use_bf16) {
        const int n2 = MROWS * EMB / 2;
        cvt_bf16<<<n2 / 256, 256, 0, stream>>>(x, xb, n2);
        wt_bf16_all<<<dim3(EMB / 32, EMB / 32, 4), 256, 0, stream>>>(
            Wq, Wk, Wv, Wo, Wqkvt, Wot);

        // fused QKV projection: Q/K -> QKb (stride 2048, +pos, Q*scl),
        // V -> Vtp transposed [bh][d][s]
        gemm_mfma_t<128><<<dim3(M / 128, 3072 / 128), 256, 0, stream>>>(
            xb, Wqkvt, QKb, Vtp, pos, 1, 3072, K);

        attn_mfma7<<<dim3(16, BATCH * NHEAD), 256, 0, stream>>>(QKb, Vtp, AOb);

        // Wo GEMM: TM=64 -> 512 blocks (2/CU)
        gemm_mfma_t<64><<<dim3(M / 64, EMB / 128), 256, 0, stream>>>(
            AOb, Wot, out, nullptr, pos, 0, EMB, K);
    } else {
        // fp32 fallback
        size_t f = 0;
        float* posf = (float*)(ws + f); f += (size_t)SEQ * DHEAD * 4;
        float* Qb = (float*)(ws + f); f += (size_t)MROWS * EMB * 4;
        float* Kb = (float*)(ws + f); f += (size_t)MROWS * EMB * 4;
        float* Vb = (float*)(ws + f); f += (size_t)MROWS * EMB * 4;
        float* AO = (float*)(ws + f);
        dim3 g(M / BM, EMB / BN);
        gemm_f32<<<g, 256, 0, stream>>>(x, Wq, Qb, posf, 1, M, EMB, K);
        gemm_f32<<<g, 256, 0, stream>>>(x, Wk, Kb, posf, 1, M, EMB, K);
        gemm_f32<<<g, 256, 0, stream>>>(x, Wv, Vb, posf, 0, M, EMB, K);
        attn_fwd<<<dim3(SEQ / QT, BATCH * NHEAD), QT, 0, stream>>>(Qb, Kb, Vb, AO);
        gemm_f32<<<g, 256, 0, stream>>>(AO, Wo, out, posf, 0, M, EMB, K);
    }
}